// Round 1
// baseline (280.832 us; speedup 1.0000x reference)
//
#include <hip/hip_runtime.h>
#include <hip/hip_cooperative_groups.h>
#include <math.h>

#define N 16384
#define MD 512
#define CTRLDIM 1024
#define OUTF 1542  // 3*512+6

namespace cg = cooperative_groups;

// ws layout (floats):
//   [0    .. 1541]   O      projection output o
//   [1552 .. 2063]   E      erase vec (16B-aligned)
//   [2064 .. 2575]   A      add vec (16B-aligned)
//   [2576 .. 3599]   PART1  per-block partial sums of exp (1024 blocks)
//   [3600 .. 4623]   PART2  per-block partial sums of wp (1024 blocks fused; 64 used by fallback)
//   [4624 .. 21007]  EZ     exp(beta*sim - beta) per row
//   [21008.. 37391]  WP     (fallback path only)

__device__ __forceinline__ float softplus_f(float x) {
    return (x > 20.f) ? x : log1pf(expf(x));
}

__device__ __forceinline__ float wave_bfly_sum(float v) {
    #pragma unroll
    for (int off = 1; off < 64; off <<= 1) v += __shfl_xor(v, off, 64);
    return v;
}

// o[row] = dot(W[row,:], emb) + b[row]; rows >= 518 also scatter into aligned E/A
__global__ void k_proj(const float* __restrict__ emb, const float* __restrict__ W,
                       const float* __restrict__ b, float* __restrict__ O,
                       float* __restrict__ E, float* __restrict__ A) {
    int row = blockIdx.x;
    int t = threadIdx.x;
    const float4* w4 = (const float4*)(W + (size_t)row * CTRLDIM);
    const float4* e4 = (const float4*)emb;
    float4 wv = w4[t];
    float4 ev = e4[t];
    float p = wv.x * ev.x + wv.y * ev.y + wv.z * ev.z + wv.w * ev.w;
    #pragma unroll
    for (int off = 32; off; off >>= 1) p += __shfl_down(p, off, 64);
    __shared__ float s[4];
    int lane = t & 63, wid = t >> 6;
    if (lane == 0) s[wid] = p;
    __syncthreads();
    if (t == 0) {
        float val = s[0] + s[1] + s[2] + s[3] + b[row];
        O[row] = val;
        if (row >= MD + 6 && row < 2 * MD + 6)      E[row - (MD + 6)] = val;
        else if (row >= 2 * MD + 6)                 A[row - (2 * MD + 6)] = val;
    }
}

// ===================== fused cooperative kernel =====================
// 1024 blocks x 256 threads, 16 rows/block. Phase A streams memory rows
// into LDS + computes EZ/PART1. grid.sync. Phase B (wave 0) does the
// shift+sharpen for the block's 16 rows -> wp in LDS + PART2. grid.sync.
// Phase C reduces PART2 redundantly per wave, normalizes, and updates the
// block's rows FROM LDS (no second HBM read of memory).
__global__ void __launch_bounds__(256, 4) k_fused(
        const float* __restrict__ mem, const float* __restrict__ O,
        const float* __restrict__ wprev, const float* __restrict__ E,
        const float* __restrict__ A, float* __restrict__ EZ,
        float* __restrict__ PART1, float* __restrict__ PART2,
        float* __restrict__ wout, float* __restrict__ outMem) {
    __shared__ float4 smem[2048];   // 16 rows x 512 floats = 32 KB
    __shared__ float wp_s[16];
    __shared__ float sred[4];

    int t = threadIdx.x, lane = t & 63, wid = t >> 6;
    int b = blockIdx.x;

    // ---------- Phase A: cosine similarity + exp ----------
    const float4* k4 = (const float4*)O;
    float4 kk0 = k4[lane], kk1 = k4[lane + 64];
    float ksq = kk0.x * kk0.x + kk0.y * kk0.y + kk0.z * kk0.z + kk0.w * kk0.w
              + kk1.x * kk1.x + kk1.y * kk1.y + kk1.z * kk1.z + kk1.w * kk1.w;
    ksq = wave_bfly_sum(ksq);
    float knorm = sqrtf(ksq);
    float beta = softplus_f(O[MD]);
    int row0 = (b * 4 + wid) * 4;
    float4 m0[4], m1[4];
    #pragma unroll
    for (int r = 0; r < 4; r++) {
        const float4* m4 = (const float4*)(mem + (size_t)(row0 + r) * MD);
        m0[r] = m4[lane];
        m1[r] = m4[lane + 64];
    }
    float wsum = 0.f;
    #pragma unroll
    for (int r = 0; r < 4; r++) {
        smem[(wid * 4 + r) * 128 + lane]      = m0[r];
        smem[(wid * 4 + r) * 128 + 64 + lane] = m1[r];
        float dot = m0[r].x * kk0.x + m0[r].y * kk0.y + m0[r].z * kk0.z + m0[r].w * kk0.w
                  + m1[r].x * kk1.x + m1[r].y * kk1.y + m1[r].z * kk1.z + m1[r].w * kk1.w;
        float nsq = m0[r].x * m0[r].x + m0[r].y * m0[r].y + m0[r].z * m0[r].z + m0[r].w * m0[r].w
                  + m1[r].x * m1[r].x + m1[r].y * m1[r].y + m1[r].z * m1[r].z + m1[r].w * m1[r].w;
        dot = wave_bfly_sum(dot);
        nsq = wave_bfly_sum(nsq);
        float z = beta * dot / (knorm * sqrtf(nsq) + 1e-16f);
        float ez = expf(z - beta);           // sim <= 1 so exponent <= 0: exact max-shift
        if (lane == 0) EZ[row0 + r] = ez;
        wsum += ez;                          // identical in all lanes
    }
    if (lane == 0) sred[wid] = wsum;
    __syncthreads();
    if (t == 0) PART1[b] = sred[0] + sred[1] + sred[2] + sred[3];

    cg::this_grid().sync();

    // ---------- Phase B: shift + sharpen (wave 0, 16 rows) ----------
    if (wid == 0) {
        float v = 0.f;
        #pragma unroll
        for (int j = 0; j < 16; j++) v += PART1[lane + j * 64];
        float inv1 = 1.f / wave_bfly_sum(v);
        float g = 1.f / (1.f + expf(-O[MD + 1]));
        float s0r = O[MD + 2], s1r = O[MD + 3], s2r = O[MD + 4];
        float mx = fmaxf(s0r, fmaxf(s1r, s2r));
        float e0 = expf(s0r - mx), e1 = expf(s1r - mx), e2 = expf(s2r - mx);
        float inv_se = 1.f / (e0 + e1 + e2);
        float s0 = e0 * inv_se, s1 = e1 * inv_se, s2 = e2 * inv_se;
        float gamma = 1.f + softplus_f(O[MD + 5]);
        float gm1 = 1.f - g;
        int r = lane & 15;                     // lanes 16..63 replicate rows (no OOB)
        int i = b * 16 + r;
        int im = (i == 0) ? (N - 1) : (i - 1);
        int ip = (i == N - 1) ? 0 : (i + 1);
        float wgm = g * EZ[im] * inv1 + gm1 * wprev[im];
        float wgc = g * EZ[i]  * inv1 + gm1 * wprev[i];
        float wgp = g * EZ[ip] * inv1 + gm1 * wprev[ip];
        float wsv = s0 * wgm + s1 * wgc + s2 * wgp;
        float wp = exp2f(gamma * log2f(wsv + 1e-16f));   // ws >= 0 always
        if (lane < 16) wp_s[r] = wp;
        float bs = wave_bfly_sum((lane < 16) ? wp : 0.f);
        if (lane == 0) PART2[b] = bs;
    }

    cg::this_grid().sync();

    // ---------- Phase C: normalize + memory update (from LDS) ----------
    float v2 = 0.f;
    #pragma unroll
    for (int j = 0; j < 16; j++) v2 += PART2[lane + j * 64];
    float inv2 = 1.f / wave_bfly_sum(v2);
    if (t < 16) wout[b * 16 + t] = wp_s[t] * inv2;
    const float4* E4 = (const float4*)E;
    const float4* A4 = (const float4*)A;
    float4* out4 = (float4*)outMem;
    #pragma unroll
    for (int q = 0; q < 8; q++) {
        int idx = t + q * 256;                  // 0..2047 float4 within block
        int rl = idx >> 7, c = idx & 127;
        float wi = wp_s[rl] * inv2;
        float4 mv = smem[idx];
        float4 e = E4[c];
        float4 a = A4[c];
        float4 o;
        o.x = mv.x * (1.f - wi * e.x) + wi * a.x;
        o.y = mv.y * (1.f - wi * e.y) + wi * a.y;
        o.z = mv.z * (1.f - wi * e.z) + wi * a.z;
        o.w = mv.w * (1.f - wi * e.w) + wi * a.w;
        out4[(size_t)b * 2048 + idx] = o;
    }
}

// ===================== fallback path (previous 4-kernel pipeline) =====================
__global__ void __launch_bounds__(256) k_sim(const float* __restrict__ mem,
                                             const float* __restrict__ O,
                                             float* __restrict__ EZ,
                                             float* __restrict__ PART1) {
    int t = threadIdx.x, lane = t & 63, wid = t >> 6;
    int waveId = blockIdx.x * 4 + wid;
    const float4* k4 = (const float4*)O;
    float4 k0 = k4[lane], k1 = k4[lane + 64];
    float ksq = k0.x * k0.x + k0.y * k0.y + k0.z * k0.z + k0.w * k0.w
              + k1.x * k1.x + k1.y * k1.y + k1.z * k1.z + k1.w * k1.w;
    ksq = wave_bfly_sum(ksq);
    float knorm = sqrtf(ksq);
    float beta = softplus_f(O[MD]);
    int row0 = waveId * 4;
    float4 m0[4], m1[4];
    #pragma unroll
    for (int r = 0; r < 4; r++) {
        const float4* m4 = (const float4*)(mem + (size_t)(row0 + r) * MD);
        m0[r] = m4[lane];
        m1[r] = m4[lane + 64];
    }
    float wsum = 0.f;
    #pragma unroll
    for (int r = 0; r < 4; r++) {
        float dot = m0[r].x * k0.x + m0[r].y * k0.y + m0[r].z * k0.z + m0[r].w * k0.w
                  + m1[r].x * k1.x + m1[r].y * k1.y + m1[r].z * k1.z + m1[r].w * k1.w;
        float nsq = m0[r].x * m0[r].x + m0[r].y * m0[r].y + m0[r].z * m0[r].z + m0[r].w * m0[r].w
                  + m1[r].x * m1[r].x + m1[r].y * m1[r].y + m1[r].z * m1[r].z + m1[r].w * m1[r].w;
        dot = wave_bfly_sum(dot);
        nsq = wave_bfly_sum(nsq);
        float z = beta * dot / (knorm * sqrtf(nsq) + 1e-16f);
        float ez = expf(z - beta);
        if (lane == 0) EZ[row0 + r] = ez;
        wsum += ez;
    }
    __shared__ float sblk[4];
    if (lane == 0) sblk[wid] = wsum;
    __syncthreads();
    if (t == 0) PART1[blockIdx.x] = sblk[0] + sblk[1] + sblk[2] + sblk[3];
}

__global__ void __launch_bounds__(256) k_shift(const float* __restrict__ EZ,
                                               const float* __restrict__ wprev,
                                               const float* __restrict__ O,
                                               const float* __restrict__ PART1,
                                               float* __restrict__ WP,
                                               float* __restrict__ PART2) {
    int t = threadIdx.x, lane = t & 63, wid = t >> 6;
    float v = 0.f;
    #pragma unroll
    for (int j = 0; j < 16; j++) v += PART1[lane + j * 64];
    float inv1 = 1.f / wave_bfly_sum(v);
    float g = 1.f / (1.f + expf(-O[MD + 1]));
    float s0r = O[MD + 2], s1r = O[MD + 3], s2r = O[MD + 4];
    float m = fmaxf(s0r, fmaxf(s1r, s2r));
    float e0 = expf(s0r - m), e1 = expf(s1r - m), e2 = expf(s2r - m);
    float inv_se = 1.f / (e0 + e1 + e2);
    float s0 = e0 * inv_se, s1 = e1 * inv_se, s2 = e2 * inv_se;
    float gamma = 1.f + softplus_f(O[MD + 5]);
    float gm1 = 1.f - g;
    int i = blockIdx.x * 256 + t;
    int im = (i == 0) ? (N - 1) : (i - 1);
    int ip = (i == N - 1) ? 0 : (i + 1);
    float wgm = g * EZ[im] * inv1 + gm1 * wprev[im];
    float wgc = g * EZ[i]  * inv1 + gm1 * wprev[i];
    float wgp = g * EZ[ip] * inv1 + gm1 * wprev[ip];
    float wsv = s0 * wgm + s1 * wgc + s2 * wgp;
    float wp = exp2f(gamma * log2f(wsv + 1e-16f));
    WP[i] = wp;
    float bs = wave_bfly_sum(wp);
    __shared__ float sblk[4];
    if (lane == 0) sblk[wid] = bs;
    __syncthreads();
    if (t == 0) PART2[blockIdx.x] = sblk[0] + sblk[1] + sblk[2] + sblk[3];
}

__global__ void __launch_bounds__(256) k_upd(const float* __restrict__ mem,
                                             const float* __restrict__ WP,
                                             const float* __restrict__ PART2,
                                             const float* __restrict__ E,
                                             const float* __restrict__ A,
                                             float* __restrict__ wout,
                                             float* __restrict__ outMem) {
    int t = threadIdx.x, lane = t & 63;
    float inv2 = 1.f / wave_bfly_sum(PART2[lane]);
    int idx = blockIdx.x * 256 + t;
    int i = idx >> 7;
    int c = idx & 127;
    float wi = WP[i] * inv2;
    if (c == 0) wout[i] = wi;
    float4 m = ((const float4*)mem)[idx];
    float4 e = ((const float4*)E)[c];
    float4 a = ((const float4*)A)[c];
    float4 o;
    o.x = m.x * (1.f - wi * e.x) + wi * a.x;
    o.y = m.y * (1.f - wi * e.y) + wi * a.y;
    o.z = m.z * (1.f - wi * e.z) + wi * a.z;
    o.w = m.w * (1.f - wi * e.w) + wi * a.w;
    ((float4*)outMem)[idx] = o;
}

extern "C" void kernel_launch(void* const* d_in, const int* in_sizes, int n_in,
                              void* d_out, int out_size, void* d_ws, size_t ws_size,
                              hipStream_t stream) {
    const float* emb   = (const float*)d_in[0];
    const float* wprev = (const float*)d_in[1];
    const float* mem   = (const float*)d_in[2];
    const float* W     = (const float*)d_in[3];
    const float* b     = (const float*)d_in[4];
    float* out = (float*)d_out;
    float* wsf = (float*)d_ws;
    float* O     = wsf;
    float* E     = wsf + 1552;
    float* A     = wsf + 2064;
    float* PART1 = wsf + 2576;
    float* PART2 = wsf + 3600;
    float* EZ    = wsf + 4624;
    float* WP    = wsf + 21008;

    k_proj<<<OUTF, 256, 0, stream>>>(emb, W, b, O, E, A);

    static int coop = -1;
    if (coop < 0) {
        int dev = 0, val = 0;
        hipGetDevice(&dev);
        hipDeviceGetAttribute(&val, hipDeviceAttributeCooperativeLaunch, dev);
        coop = val;
    }

    bool done = false;
    if (coop) {
        const float* memp = mem;  const float* Op = O;  const float* wprevp = wprev;
        const float* Ep = E;      const float* Ap = A;
        float* EZp = EZ; float* P1p = PART1; float* P2p = PART2;
        float* woutp = out; float* outMemp = out + N;
        void* args[] = {(void*)&memp, (void*)&Op, (void*)&wprevp, (void*)&Ep, (void*)&Ap,
                        (void*)&EZp, (void*)&P1p, (void*)&P2p, (void*)&woutp, (void*)&outMemp};
        hipError_t err = hipLaunchCooperativeKernel((const void*)k_fused,
                                                    dim3(1024), dim3(256), args, 0, stream);
        done = (err == hipSuccess);
    }
    if (!done) {
        k_sim<<<N / 16, 256, 0, stream>>>(mem, O, EZ, PART1);
        k_shift<<<N / 256, 256, 0, stream>>>(EZ, wprev, O, PART1, WP, PART2);
        k_upd<<<(N * (MD / 4)) / 256, 256, 0, stream>>>(mem, WP, PART2, E, A, out, out + N);
    }
}

// Round 2
// 109.784 us; speedup vs baseline: 2.5580x; 2.5580x over previous
//
#include <hip/hip_runtime.h>
#include <math.h>

#define N 16384
#define MD 512
#define CTRLDIM 1024
#define OUTF 1542  // 3*512+6

// ws layout (floats):
//   [0    .. 1541]   O      projection output o
//   [1552 .. 2063]   E      erase vec (16B-aligned)
//   [2064 .. 2575]   A      add vec (16B-aligned)
//   [2576 .. 3599]   PART1  per-block partial sums of exp (k_sim, 1024 blocks)
//   [3600 .. 3663]   PART2  per-block partial sums of wp (k_shift, 64 blocks)
//   [3664 .. 20047]  EZ     exp(beta*sim - beta) per row
//   [20048.. 36431]  WP     (ws+eps)^gamma per row
// No atomics anywhere: partials written to private slots; consumers reduce
// redundantly per-wave (butterfly shuffle -> every lane has the total).
//
// NOTE (R1 post-mortem): cooperative-kernel fusion of sim+shift+upd was tried
// and regressed 110 -> 281 us: cg::this_grid().sync() at 1024 blocks costs
// ~80 us per sync on gfx950 (spin over device-scope flags across 8 XCDs),
// vs ~2 us for the kernel boundaries it replaces. Do not re-attempt.

__device__ __forceinline__ float softplus_f(float x) {
    return (x > 20.f) ? x : log1pf(expf(x));
}

__device__ __forceinline__ float wave_bfly_sum(float v) {
    #pragma unroll
    for (int off = 1; off < 64; off <<= 1) v += __shfl_xor(v, off, 64);
    return v;
}

// One row per wave, 4 waves/block: lane reads 4 float4 of W-row + emb,
// butterfly reduce within the wave only (no LDS, no __syncthreads).
__global__ void __launch_bounds__(256) k_proj(const float* __restrict__ emb,
                                              const float* __restrict__ W,
                                              const float* __restrict__ b,
                                              float* __restrict__ O,
                                              float* __restrict__ E,
                                              float* __restrict__ A) {
    int t = threadIdx.x, lane = t & 63, wid = t >> 6;
    int row = blockIdx.x * 4 + wid;
    if (row >= OUTF) return;                    // wave-uniform
    const float4* w4 = (const float4*)(W + (size_t)row * CTRLDIM);
    const float4* e4 = (const float4*)emb;
    float p = 0.f;
    #pragma unroll
    for (int s = 0; s < 4; s++) {
        float4 wv = w4[lane + s * 64];
        float4 ev = e4[lane + s * 64];
        p += wv.x * ev.x + wv.y * ev.y + wv.z * ev.z + wv.w * ev.w;
    }
    p = wave_bfly_sum(p);
    if (lane == 0) {
        float val = p + b[row];
        O[row] = val;
        if (row >= MD + 6 && row < 2 * MD + 6)      E[row - (MD + 6)] = val;
        else if (row >= 2 * MD + 6)                 A[row - (2 * MD + 6)] = val;
    }
}

// wave per 4 rows: EZ[row] = exp(beta*sim - beta); block partial -> PART1[blk]
// (sim <= 1 so exponent <= 0: the softmax max-shift by beta is exact & free)
__global__ void __launch_bounds__(256) k_sim(const float* __restrict__ mem,
                                             const float* __restrict__ O,
                                             float* __restrict__ EZ,
                                             float* __restrict__ PART1) {
    int t = threadIdx.x, lane = t & 63, wid = t >> 6;
    int waveId = blockIdx.x * 4 + wid;  // 0..4095
    const float4* k4 = (const float4*)O;
    float4 k0 = k4[lane], k1 = k4[lane + 64];
    float ksq = k0.x * k0.x + k0.y * k0.y + k0.z * k0.z + k0.w * k0.w
              + k1.x * k1.x + k1.y * k1.y + k1.z * k1.z + k1.w * k1.w;
    ksq = wave_bfly_sum(ksq);
    float knorm = sqrtf(ksq);
    float beta = softplus_f(O[MD]);
    int row0 = waveId * 4;
    float4 m0[4], m1[4];
    #pragma unroll
    for (int r = 0; r < 4; r++) {
        const float4* m4 = (const float4*)(mem + (size_t)(row0 + r) * MD);
        m0[r] = m4[lane];
        m1[r] = m4[lane + 64];
    }
    float wsum = 0.f;
    #pragma unroll
    for (int r = 0; r < 4; r++) {
        float dot = m0[r].x * k0.x + m0[r].y * k0.y + m0[r].z * k0.z + m0[r].w * k0.w
                  + m1[r].x * k1.x + m1[r].y * k1.y + m1[r].z * k1.z + m1[r].w * k1.w;
        float nsq = m0[r].x * m0[r].x + m0[r].y * m0[r].y + m0[r].z * m0[r].z + m0[r].w * m0[r].w
                  + m1[r].x * m1[r].x + m1[r].y * m1[r].y + m1[r].z * m1[r].z + m1[r].w * m1[r].w;
        dot = wave_bfly_sum(dot);
        nsq = wave_bfly_sum(nsq);
        float z = beta * dot / (knorm * sqrtf(nsq) + 1e-16f);
        float ez = expf(z - beta);
        if (lane == 0) EZ[row0 + r] = ez;
        wsum += ez;  // identical in all lanes
    }
    __shared__ float sblk[4];
    if (lane == 0) sblk[wid] = wsum;
    __syncthreads();
    if (t == 0) PART1[blockIdx.x] = sblk[0] + sblk[1] + sblk[2] + sblk[3];
}

// grid-wide: SUM1 from PART1 (per-wave redundant reduce) -> wc -> wg ->
// circular 3-tap shift -> wp=(ws+eps)^gamma -> PART2[blk]
__global__ void __launch_bounds__(256) k_shift(const float* __restrict__ EZ,
                                               const float* __restrict__ wprev,
                                               const float* __restrict__ O,
                                               const float* __restrict__ PART1,
                                               float* __restrict__ WP,
                                               float* __restrict__ PART2) {
    int t = threadIdx.x, lane = t & 63, wid = t >> 6;
    float v = 0.f;
    #pragma unroll
    for (int j = 0; j < 16; j++) v += PART1[lane + j * 64];
    float inv1 = 1.f / wave_bfly_sum(v);
    // uniform scalars, recomputed per thread (cheap)
    float g = 1.f / (1.f + expf(-O[MD + 1]));
    float s0r = O[MD + 2], s1r = O[MD + 3], s2r = O[MD + 4];
    float m = fmaxf(s0r, fmaxf(s1r, s2r));
    float e0 = expf(s0r - m), e1 = expf(s1r - m), e2 = expf(s2r - m);
    float inv_se = 1.f / (e0 + e1 + e2);
    float s0 = e0 * inv_se, s1 = e1 * inv_se, s2 = e2 * inv_se;
    float gamma = 1.f + softplus_f(O[MD + 5]);
    float gm1 = 1.f - g;
    int i = blockIdx.x * 256 + t;
    int im = (i == 0) ? (N - 1) : (i - 1);
    int ip = (i == N - 1) ? 0 : (i + 1);
    float wgm = g * EZ[im] * inv1 + gm1 * wprev[im];
    float wgc = g * EZ[i]  * inv1 + gm1 * wprev[i];
    float wgp = g * EZ[ip] * inv1 + gm1 * wprev[ip];
    float wsv = s0 * wgm + s1 * wgc + s2 * wgp;
    float wp = exp2f(gamma * log2f(wsv + 1e-16f));  // ws >= 0 always
    WP[i] = wp;
    float bs = wave_bfly_sum(wp);
    __shared__ float sblk[4];
    if (lane == 0) sblk[wid] = bs;
    __syncthreads();
    if (t == 0) PART2[blockIdx.x] = sblk[0] + sblk[1] + sblk[2] + sblk[3];
}

// SUM2 from PART2 (per-wave reduce); w = WP/SUM2 -> out;
// new_memory = memory * (1 - w_i*e_j) + w_i*a_j
__global__ void __launch_bounds__(256) k_upd(const float* __restrict__ mem,
                                             const float* __restrict__ WP,
                                             const float* __restrict__ PART2,
                                             const float* __restrict__ E,
                                             const float* __restrict__ A,
                                             float* __restrict__ wout,
                                             float* __restrict__ outMem) {
    int t = threadIdx.x, lane = t & 63;
    float inv2 = 1.f / wave_bfly_sum(PART2[lane]);  // exactly 64 entries
    int idx = blockIdx.x * 256 + t;                 // float4 units
    int i = idx >> 7;
    int c = idx & 127;
    float wi = WP[i] * inv2;
    if (c == 0) wout[i] = wi;
    float4 m = ((const float4*)mem)[idx];
    float4 e = ((const float4*)E)[c];
    float4 a = ((const float4*)A)[c];
    float4 o;
    o.x = m.x * (1.f - wi * e.x) + wi * a.x;
    o.y = m.y * (1.f - wi * e.y) + wi * a.y;
    o.z = m.z * (1.f - wi * e.z) + wi * a.z;
    o.w = m.w * (1.f - wi * e.w) + wi * a.w;
    ((float4*)outMem)[idx] = o;
}

extern "C" void kernel_launch(void* const* d_in, const int* in_sizes, int n_in,
                              void* d_out, int out_size, void* d_ws, size_t ws_size,
                              hipStream_t stream) {
    const float* emb   = (const float*)d_in[0];
    const float* wprev = (const float*)d_in[1];
    const float* mem   = (const float*)d_in[2];
    const float* W     = (const float*)d_in[3];
    const float* b     = (const float*)d_in[4];
    float* out = (float*)d_out;
    float* wsf = (float*)d_ws;
    float* O     = wsf;
    float* E     = wsf + 1552;
    float* A     = wsf + 2064;
    float* PART1 = wsf + 2576;
    float* PART2 = wsf + 3600;
    float* EZ    = wsf + 3664;
    float* WP    = wsf + 20048;

    k_proj<<<(OUTF + 3) / 4, 256, 0, stream>>>(emb, W, b, O, E, A);            // 386 blocks
    k_sim<<<N / 16, 256, 0, stream>>>(mem, O, EZ, PART1);                      // 1024 blocks
    k_shift<<<N / 256, 256, 0, stream>>>(EZ, wprev, O, PART1, WP, PART2);      // 64 blocks
    k_upd<<<(N * (MD / 4)) / 256, 256, 0, stream>>>(mem, WP, PART2, E, A, out, out + N);
}